// Round 4
// baseline (150.044 us; speedup 1.0000x reference)
//
#include <hip/hip_runtime.h>

// Hadamard transform along channel dim of NCHW fp32 tensor (FWHT_1024 = H_32 (x) H_32).
// x: [32, 1024, 32, 32] fp32; out[b,d,s] = sum_c x[b,c,s] * (-1)^popc(c&d) / 32.
//
// R4: persistent blocks + register prefetch + lgkmcnt-only barriers (R2 structure),
// with STRIDED chunk mapping: iteration it of block p does chunk g = it*GRID + p.
// R2/R3's consecutive-chunks-per-block wrote the two 64B halves of each 128B
// output line one iteration (~35us) apart; per-XCD write set per iteration
// (64 blk x 64KB = 4MB) == L2 size, so half-dirty lines evicted before merging ->
// partial-line RMW (WRITE 131->283MB, FETCH +84MB). Strided mapping restores
// R1's pairing: adjacent blocks write adjacent halves concurrently (WRITE was
// exactly ideal in R1).
//
// LDS swizzle: channel c=(i<<5)|j stored at slot (i<<5)|(j^i) -> every LDS access
// in both passes is exactly 2-way bank aliased (free on CDNA4). Verified:
// SQ_LDS_BANK_CONFLICT == 0.

constexpr int C       = 1024;
constexpr int SPATIAL = 1024;   // 32*32, contiguous innermost
constexpr int S       = 16;     // spatial positions per chunk (64B per channel row)
constexpr int BLOCK   = 512;
constexpr int ITERS   = 4;
constexpr int GRID    = 32 * (SPATIAL / S) / ITERS;   // 512 = 2 blocks/CU

__device__ __forceinline__ void lds_barrier() {
    // Wait only for LDS ops; do NOT drain vmcnt (prefetch loads / draining stores).
    asm volatile("s_waitcnt lgkmcnt(0)" ::: "memory");
    __builtin_amdgcn_s_barrier();
}

__global__ __launch_bounds__(BLOCK, 4) void hadamard_fwht_kernel(
    const float* __restrict__ x, float* __restrict__ out)
{
    __shared__ float lds[C * S];   // 64 KiB -> 2 blocks/CU

    const int t = threadIdx.x;
    const int p = blockIdx.x;

    float4 r[8];   // prefetch buffer: this thread's 128B of the chunk

    auto issue_loads = [&](int g) {
        const int b = g >> 6, chunk = g & 63;
        const size_t base = ((size_t)b * C) * SPATIAL + (size_t)chunk * S;
        #pragma unroll
        for (int k = 0; k < 8; ++k) {
            const int idx4 = t + (k << 9);          // [0, 4096)
            const int c    = idx4 >> 2;
            const int s4   = idx4 & 3;
            r[k] = *reinterpret_cast<const float4*>(
                x + base + (size_t)c * SPATIAL + (s4 << 2));
        }
    };

    issue_loads(p);   // it = 0

    for (int it = 0; it < ITERS; ++it) {
        const int g = it * GRID + p;               // strided: neighbors stay neighbors
        const int b = g >> 6, chunk = g & 63;
        const size_t base = ((size_t)b * C) * SPATIAL + (size_t)chunk * S;

        // ---- commit prefetched regs -> LDS (swizzled) ----
        #pragma unroll
        for (int k = 0; k < 8; ++k) {
            const int idx4 = t + (k << 9);
            const int c    = idx4 >> 2;
            const int s4   = idx4 & 3;
            const int i    = c >> 5;
            const int j    = c & 31;
            const int cs   = (i << 5) | (j ^ i);
            *reinterpret_cast<float4*>(&lds[(cs << 4) + (s4 << 2)]) = r[k];
        }
        lds_barrier();

        // ---- prefetch next chunk (overlaps pass1+pass2 compute) ----
        if (it + 1 < ITERS) issue_loads((it + 1) * GRID + p);

        float v[32];

        // ---- pass 1: FWHT_32 along i; thread (j,s) reads+writes its own slots ----
        {
            const int j = t >> 4;
            const int s = t & 15;
            #pragma unroll
            for (int i = 0; i < 32; ++i)
                v[i] = lds[(((i << 5) | (j ^ i)) << 4) + s];

            #pragma unroll
            for (int m = 1; m < 32; m <<= 1)
                #pragma unroll
                for (int gg = 0; gg < 32; gg += (m << 1))
                    #pragma unroll
                    for (int a = gg; a < gg + m; ++a) {
                        const float pp = v[a], q = v[a + m];
                        v[a]     = pp + q;
                        v[a + m] = pp - q;
                    }

            #pragma unroll
            for (int i = 0; i < 32; ++i)
                lds[(((i << 5) | (j ^ i)) << 4) + s] = v[i];
        }
        lds_barrier();

        // ---- pass 2: FWHT_32 along j; scale 1/32; plain store ----
        {
            const int i = t >> 4;
            const int s = t & 15;
            #pragma unroll
            for (int j = 0; j < 32; ++j)
                v[j] = lds[(((i << 5) | (j ^ i)) << 4) + s];

            #pragma unroll
            for (int m = 1; m < 32; m <<= 1)
                #pragma unroll
                for (int gg = 0; gg < 32; gg += (m << 1))
                    #pragma unroll
                    for (int a = gg; a < gg + m; ++a) {
                        const float pp = v[a], q = v[a + m];
                        v[a]     = pp + q;
                        v[a + m] = pp - q;
                    }

            const float scale = 1.0f / 32.0f;
            float* o = out + base + ((size_t)(i << 5)) * SPATIAL + s;
            #pragma unroll
            for (int j = 0; j < 32; ++j)
                o[(size_t)j * SPATIAL] = v[j] * scale;
        }
        lds_barrier();   // protect LDS from next iteration's writes
    }
}

extern "C" void kernel_launch(void* const* d_in, const int* in_sizes, int n_in,
                              void* d_out, int out_size, void* d_ws, size_t ws_size,
                              hipStream_t stream) {
    const float* x = (const float*)d_in[0];
    float* out = (float*)d_out;
    hadamard_fwht_kernel<<<dim3(GRID), dim3(BLOCK), 0, stream>>>(x, out);
}

// Round 5
// 68.639 us; speedup vs baseline: 2.1860x; 2.1860x over previous
//
#include <hip/hip_runtime.h>
#include <stdint.h>

// Hadamard transform along channel dim of NCHW fp32 tensor (FWHT_1024 = H_32 (x) H_32).
// x: [32, 1024, 32, 32] fp32; out[b,d,s] = sum_c x[b,c,s] * (-1)^popc(c&d) / 32.
//
// R5: persistent 256 blocks (1/CU), 2 x 64KiB LDS double-buffer, async staging via
// global_load_lds (width 16) -- zero VGPR cost, so no spill (R2-R4's register
// prefetch spilled ~32 VGPRs -> ~270MB scratch traffic, the real source of the
// WRITE 131->276MB / FETCH 131->216MB amplification). Counted s_waitcnt vmcnt(40)
// (32 stores + 8 next-chunk loads in flight) + raw barriers keep prefetch loads
// live across barriers (T3/T4 pattern).
//
// global_load_lds writes LDS linearly (wave base + lane*16), so the LDS layout is
// linear and the bank-conflict swizzle is applied on the GLOBAL source address
// instead: slot row c_lin holds channel c = unswz(c_lin); swz(i,j)=(i,j^i) is an
// involution. Compute phases read slot ((i<<5)|(j^i)) exactly as R1 (verified
// SQ_LDS_BANK_CONFLICT == 0, exactly 2-way bank aliasing everywhere).

constexpr int C       = 1024;
constexpr int SPATIAL = 1024;   // 32*32 contiguous innermost
constexpr int S       = 16;     // spatial positions per chunk (64B per channel row)
constexpr int BLOCK   = 512;
constexpr int ITERS   = 8;
constexpr int GRID    = 32 * (SPATIAL / S) / ITERS;   // 256 = 1 block/CU (128KiB LDS)

typedef __attribute__((address_space(3))) uint32_t       lds_u32;
typedef const __attribute__((address_space(1))) uint32_t glb_u32;

__global__ __launch_bounds__(BLOCK, 2) void hadamard_fwht_kernel(
    const float* __restrict__ x, float* __restrict__ out)
{
    __shared__ float lds[2][C * S];   // 128 KiB

    const int t = threadIdx.x;
    const int p = blockIdx.x;

    // Stage one 64KiB chunk into LDS buffer `buf` via direct HBM->LDS.
    // 8 issues/thread x 16B; LDS dest linear in (c_lin, s4); global source
    // pre-swizzled: slot c_lin <- channel (i<<5)|(jl^i).
    auto stage = [&](int g, int buf) {
        const int b = g >> 6, chunk = g & 63;
        const float* src = x + ((size_t)b * C) * SPATIAL + (size_t)chunk * S;
        #pragma unroll
        for (int k = 0; k < 8; ++k) {
            const int idx4  = (k << 9) + t;        // 16B-unit index in buffer
            const int c_lin = idx4 >> 2;           // destination slot row
            const int s4    = t & 3;               // float4 slot within 16-float row
            const int i     = c_lin >> 5;
            const int jl    = c_lin & 31;
            const int c     = (i << 5) | (jl ^ i); // source channel (involution)
            const float* gp = src + (size_t)c * SPATIAL + (s4 << 2);
            // wave-uniform LDS base (HW adds lane*16): 16B-unit (k*512 + wave*64)
            float* lp = &lds[buf][(size_t)((k << 9) + (t & ~63)) << 2];
            __builtin_amdgcn_global_load_lds((glb_u32*)gp, (lds_u32*)lp, 16, 0, 0);
        }
    };

    stage(p, 0);              // chunk for it=0
    stage(GRID + p, 1);       // chunk for it=1

    float v[32];
    const float scale = 1.0f / 32.0f;

    for (int it = 0; it < ITERS; ++it) {
        const int buf = it & 1;
        const int g   = it * GRID + p;             // strided: neighbors stay neighbors
        const int b = g >> 6, chunk = g & 63;
        const size_t base = ((size_t)b * C) * SPATIAL + (size_t)chunk * S;

        // Wait for THIS chunk's 8 staging loads; newer ops stay in flight:
        // it==0: only chunk1's 8 loads are newer -> vmcnt(8)
        // it>=1: 32 stores (prev iter) + 8 loads (next chunk) are newer -> vmcnt(40)
        if (it == 0) asm volatile("s_waitcnt vmcnt(8)" ::: "memory");
        else         asm volatile("s_waitcnt vmcnt(40)" ::: "memory");
        __builtin_amdgcn_s_barrier();

        const int jj = t >> 4;       // pass-1 role: (j, s); pass-2 role: (i, s)
        const int s  = t & 15;

        // ---- pass 1: FWHT_32 along i, in place ----
        #pragma unroll
        for (int i = 0; i < 32; ++i)
            v[i] = lds[buf][(((i << 5) | (jj ^ i)) << 4) + s];
        #pragma unroll
        for (int m = 1; m < 32; m <<= 1)
            #pragma unroll
            for (int gg = 0; gg < 32; gg += (m << 1))
                #pragma unroll
                for (int a = gg; a < gg + m; ++a) {
                    const float pp = v[a], q = v[a + m];
                    v[a]     = pp + q;
                    v[a + m] = pp - q;
                }
        #pragma unroll
        for (int i = 0; i < 32; ++i)
            lds[buf][(((i << 5) | (jj ^ i)) << 4) + s] = v[i];

        asm volatile("s_waitcnt lgkmcnt(0)" ::: "memory");
        __builtin_amdgcn_s_barrier();

        // ---- pass 2: FWHT_32 along j; scale; plain stores (64B segments) ----
        #pragma unroll
        for (int j = 0; j < 32; ++j)
            v[j] = lds[buf][(((jj << 5) | (j ^ jj)) << 4) + s];
        #pragma unroll
        for (int m = 1; m < 32; m <<= 1)
            #pragma unroll
            for (int gg = 0; gg < 32; gg += (m << 1))
                #pragma unroll
                for (int a = gg; a < gg + m; ++a) {
                    const float pp = v[a], q = v[a + m];
                    v[a]     = pp + q;
                    v[a + m] = pp - q;
                }
        {
            float* o = out + base + ((size_t)(jj << 5)) * SPATIAL + s;
            #pragma unroll
            for (int j = 0; j < 32; ++j)
                o[(size_t)j * SPATIAL] = v[j] * scale;
        }

        // All waves done reading buf -> safe to restage it for chunk it+2.
        asm volatile("s_waitcnt lgkmcnt(0)" ::: "memory");
        __builtin_amdgcn_s_barrier();

        if (it + 2 < ITERS) stage((it + 2) * GRID + p, buf);
    }
}

extern "C" void kernel_launch(void* const* d_in, const int* in_sizes, int n_in,
                              void* d_out, int out_size, void* d_ws, size_t ws_size,
                              hipStream_t stream) {
    const float* x = (const float*)d_in[0];
    float* out = (float*)d_out;
    hadamard_fwht_kernel<<<dim3(GRID), dim3(BLOCK), 0, stream>>>(x, out);
}

// Round 6
// 47.637 us; speedup vs baseline: 3.1497x; 1.4409x over previous
//
#include <hip/hip_runtime.h>
#include <stdint.h>

// Hadamard transform along channel dim of NCHW fp32 tensor (FWHT_1024 = H_32 (x) H_32).
// x: [32, 1024, 32, 32] fp32; out[b,d,s] = sum_c x[b,c,s] * (-1)^popc(c&d) / 32.
//
// R6: full-line chunks. S=32 spatial per chunk -> every global access is a full
// 128B line from a single instruction: staging wave-instrs read 1KB contiguous
// (8 lines), store wave-instrs write 2 full lines. R1/R5 (S=16) had 64B granules
// needing cross-block L2 merge and gave only ~4 TB/s with exactly-ideal traffic.
//
// BLOCK=1024 (16 waves/CU), single 128KiB LDS tile [c][32], GRID=256 persistent,
// ITERS=4. No swizzle needed: with 32-float rows, every pass access has
// bank = s, exactly 2 lanes/bank (free on CDNA4). Pipeline: after pass-2's
// LDS->reg reads, the whole tile is in registers, so next chunk's
// global_load_lds is issued before the butterfly+store tail; vmcnt(32) at the
// iteration top leaves the 32 stores in flight (T3/T4 counted-waitcnt pattern).

constexpr int C       = 1024;
constexpr int SPATIAL = 1024;   // 32*32 contiguous innermost
constexpr int S       = 32;     // spatial positions per chunk (128B per channel row)
constexpr int BLOCK   = 1024;
constexpr int ITERS   = 4;
constexpr int GRID    = 256;    // 1 block/CU; 32 batches * 32 chunks / 4 iters

typedef __attribute__((address_space(3))) uint32_t       lds_u32;
typedef const __attribute__((address_space(1))) uint32_t glb_u32;

__global__ __launch_bounds__(BLOCK) void hadamard_fwht_kernel(
    const float* __restrict__ x, float* __restrict__ out)
{
    __shared__ float lds[C * S];   // 128 KiB, layout [c][32]

    const int t = threadIdx.x;
    const int p = blockIdx.x;

    // Stage one 128KiB chunk: 8 x 16B per thread, fully linear.
    // Per wave-instr: lanes cover 8 channel rows x 128B contiguous = 1KB.
    auto stage = [&](int g) {
        const int b = g >> 5, chunk = g & 31;
        const float* src = x + ((size_t)b * C) * SPATIAL + (size_t)chunk * S;
        #pragma unroll
        for (int k = 0; k < 8; ++k) {
            const int idx = (k << 10) + t;       // 16B-unit index [0, 8192)
            const int c   = idx >> 3;            // channel row
            const int s4  = t & 7;               // 16B slot within the 128B row
            const float* gp = src + (size_t)c * SPATIAL + (s4 << 2);
            // wave-uniform LDS base (HW adds lane*16B): unit (k*1024 + wave*64)
            float* lp = &lds[(size_t)((k << 10) + (t & ~63)) << 2];
            __builtin_amdgcn_global_load_lds((glb_u32*)gp, (lds_u32*)lp, 16, 0, 0);
        }
    };

    stage(p);   // chunk for it = 0

    float v[32];
    const int jj = t >> 5;    // pass1: j-role; pass2: i-role
    const int s  = t & 31;
    const float scale = 1.0f / 32.0f;

    for (int it = 0; it < ITERS; ++it) {
        const int g = it * GRID + p;             // strided: 8 whole batches/iteration
        const int b = g >> 5, chunk = g & 31;
        const size_t base = ((size_t)b * C) * SPATIAL + (size_t)chunk * S;

        // Wait for THIS chunk's 8 staging loads; prev iter's 32 stores are
        // younger and stay in flight.
        if (it == 0) asm volatile("s_waitcnt vmcnt(0)" ::: "memory");
        else         asm volatile("s_waitcnt vmcnt(32)" ::: "memory");
        __builtin_amdgcn_s_barrier();

        // ---- pass 1: FWHT_32 along i (rows (i<<5)|jj), in place ----
        #pragma unroll
        for (int i = 0; i < 32; ++i)
            v[i] = lds[(((i << 5) | jj) << 5) + s];
        #pragma unroll
        for (int m = 1; m < 32; m <<= 1)
            #pragma unroll
            for (int gg = 0; gg < 32; gg += (m << 1))
                #pragma unroll
                for (int a = gg; a < gg + m; ++a) {
                    const float pp = v[a], q = v[a + m];
                    v[a]     = pp + q;
                    v[a + m] = pp - q;
                }
        #pragma unroll
        for (int i = 0; i < 32; ++i)
            lds[(((i << 5) | jj) << 5) + s] = v[i];

        asm volatile("s_waitcnt lgkmcnt(0)" ::: "memory");
        __builtin_amdgcn_s_barrier();

        // ---- pass 2 read: rows (jj<<5)|j -> whole tile now in registers ----
        #pragma unroll
        for (int j = 0; j < 32; ++j)
            v[j] = lds[(((jj << 5) | j) << 5) + s];

        asm volatile("s_waitcnt lgkmcnt(0)" ::: "memory");
        __builtin_amdgcn_s_barrier();            // all reads landed -> LDS is free

        // ---- prefetch next chunk into LDS while we butterfly + store ----
        if (it + 1 < ITERS) stage((it + 1) * GRID + p);

        #pragma unroll
        for (int m = 1; m < 32; m <<= 1)
            #pragma unroll
            for (int gg = 0; gg < 32; gg += (m << 1))
                #pragma unroll
                for (int a = gg; a < gg + m; ++a) {
                    const float pp = v[a], q = v[a + m];
                    v[a]     = pp + q;
                    v[a + m] = pp - q;
                }

        // Store: per instr, lanes = 2 channel rows x 32 s = 2 full 128B lines.
        float* o = out + base + ((size_t)(jj << 5)) * SPATIAL + s;
        #pragma unroll
        for (int j = 0; j < 32; ++j)
            o[(size_t)j * SPATIAL] = v[j] * scale;
    }
}

extern "C" void kernel_launch(void* const* d_in, const int* in_sizes, int n_in,
                              void* d_out, int out_size, void* d_ws, size_t ws_size,
                              hipStream_t stream) {
    const float* x = (const float*)d_in[0];
    float* out = (float*)d_out;
    hadamard_fwht_kernel<<<dim3(GRID), dim3(BLOCK), 0, stream>>>(x, out);
}

// Round 7
// 47.532 us; speedup vs baseline: 3.1567x; 1.0022x over previous
//
#include <hip/hip_runtime.h>
#include <stdint.h>

// Hadamard transform along channel dim of NCHW fp32 tensor (FWHT_1024 = H_32 (x) H_32).
// x: [32, 1024, 32, 32] fp32; out[b,d,s] = sum_c x[b,c,s] * (-1)^popc(c&d) / 32.
//
// R7 = R6 + nontemporal stores.
// R6 (full-line chunks, S=32): 47.6us, FETCH 65.6MB (input half-resident in L3
// across graph replays), WRITE 131MB exact. Plain stores write-allocate 131MB
// of output into L3 every replay, evicting half the input. NT stores keep the
// output out of the cache hierarchy so the 131MB input stays L3-resident.
// Safe now (unlike R2): every store instruction covers complete 128B lines
// (2 rows x 32 lanes x 4B), so no partial-line RMW is possible.
//
// Structure: BLOCK=1024 (16 waves/CU), single 128KiB LDS tile [c][32], GRID=256
// persistent, ITERS=4, staging via global_load_lds width-16 (zero VGPR cost),
// counted vmcnt leaves stores + prefetch in flight across barriers. No LDS
// swizzle needed: every pass access is exactly 2 lanes/bank (free on CDNA4).

constexpr int C       = 1024;
constexpr int SPATIAL = 1024;   // 32*32 contiguous innermost
constexpr int S       = 32;     // spatial positions per chunk (128B per channel row)
constexpr int BLOCK   = 1024;
constexpr int ITERS   = 4;
constexpr int GRID    = 256;    // 1 block/CU; 32 batches * 32 chunks / 4 iters

typedef __attribute__((address_space(3))) uint32_t       lds_u32;
typedef const __attribute__((address_space(1))) uint32_t glb_u32;

__global__ __launch_bounds__(BLOCK) void hadamard_fwht_kernel(
    const float* __restrict__ x, float* __restrict__ out)
{
    __shared__ float lds[C * S];   // 128 KiB, layout [c][32]

    const int t = threadIdx.x;
    const int p = blockIdx.x;

    // Stage one 128KiB chunk: 8 x 16B per thread, fully linear.
    // Per wave-instr: lanes cover 8 channel rows x 128B contiguous = 1KB.
    auto stage = [&](int g) {
        const int b = g >> 5, chunk = g & 31;
        const float* src = x + ((size_t)b * C) * SPATIAL + (size_t)chunk * S;
        #pragma unroll
        for (int k = 0; k < 8; ++k) {
            const int idx = (k << 10) + t;       // 16B-unit index [0, 8192)
            const int c   = idx >> 3;            // channel row
            const int s4  = t & 7;               // 16B slot within the 128B row
            const float* gp = src + (size_t)c * SPATIAL + (s4 << 2);
            // wave-uniform LDS base (HW adds lane*16B): unit (k*1024 + wave*64)
            float* lp = &lds[(size_t)((k << 10) + (t & ~63)) << 2];
            __builtin_amdgcn_global_load_lds((glb_u32*)gp, (lds_u32*)lp, 16, 0, 0);
        }
    };

    stage(p);   // chunk for it = 0

    float v[32];
    const int jj = t >> 5;    // pass1: j-role; pass2: i-role
    const int s  = t & 31;
    const float scale = 1.0f / 32.0f;

    for (int it = 0; it < ITERS; ++it) {
        const int g = it * GRID + p;             // strided: 8 whole batches/iteration
        const int b = g >> 5, chunk = g & 31;
        const size_t base = ((size_t)b * C) * SPATIAL + (size_t)chunk * S;

        // Wait for THIS chunk's 8 staging loads; prev iter's 32 stores are
        // younger and stay in flight.
        if (it == 0) asm volatile("s_waitcnt vmcnt(0)" ::: "memory");
        else         asm volatile("s_waitcnt vmcnt(32)" ::: "memory");
        __builtin_amdgcn_s_barrier();

        // ---- pass 1: FWHT_32 along i (rows (i<<5)|jj), in place ----
        #pragma unroll
        for (int i = 0; i < 32; ++i)
            v[i] = lds[(((i << 5) | jj) << 5) + s];
        #pragma unroll
        for (int m = 1; m < 32; m <<= 1)
            #pragma unroll
            for (int gg = 0; gg < 32; gg += (m << 1))
                #pragma unroll
                for (int a = gg; a < gg + m; ++a) {
                    const float pp = v[a], q = v[a + m];
                    v[a]     = pp + q;
                    v[a + m] = pp - q;
                }
        #pragma unroll
        for (int i = 0; i < 32; ++i)
            lds[(((i << 5) | jj) << 5) + s] = v[i];

        asm volatile("s_waitcnt lgkmcnt(0)" ::: "memory");
        __builtin_amdgcn_s_barrier();

        // ---- pass 2 read: rows (jj<<5)|j -> whole tile now in registers ----
        #pragma unroll
        for (int j = 0; j < 32; ++j)
            v[j] = lds[(((jj << 5) | j) << 5) + s];

        asm volatile("s_waitcnt lgkmcnt(0)" ::: "memory");
        __builtin_amdgcn_s_barrier();            // all reads landed -> LDS is free

        // ---- prefetch next chunk into LDS while we butterfly + store ----
        if (it + 1 < ITERS) stage((it + 1) * GRID + p);

        #pragma unroll
        for (int m = 1; m < 32; m <<= 1)
            #pragma unroll
            for (int gg = 0; gg < 32; gg += (m << 1))
                #pragma unroll
                for (int a = gg; a < gg + m; ++a) {
                    const float pp = v[a], q = v[a + m];
                    v[a]     = pp + q;
                    v[a + m] = pp - q;
                }

        // NT store: per instr, lanes cover 2 complete 128B lines -> no RMW,
        // and the output does not evict the L3-resident input.
        float* o = out + base + ((size_t)(jj << 5)) * SPATIAL + s;
        #pragma unroll
        for (int j = 0; j < 32; ++j)
            __builtin_nontemporal_store(v[j] * scale, &o[(size_t)j * SPATIAL]);
    }
}

extern "C" void kernel_launch(void* const* d_in, const int* in_sizes, int n_in,
                              void* d_out, int out_size, void* d_ws, size_t ws_size,
                              hipStream_t stream) {
    const float* x = (const float*)d_in[0];
    float* out = (float*)d_out;
    hadamard_fwht_kernel<<<dim3(GRID), dim3(BLOCK), 0, stream>>>(x, out);
}